// Round 1
// baseline (1559.696 us; speedup 1.0000x reference)
//
#include <hip/hip_runtime.h>

namespace {
constexpr int Bn = 2, Cin = 64, Cout = 64;
constexpr int Dd = 8, Hh = 48, Wd = 48;
constexpr int K = 27;
constexpr int SP = Dd * Hh * Wd;   // 18432
constexpr int PLANE = Hh * Wd;     // 2304
}

// x [B,C,D,H,W] -> xT [B, spatial, C]  (channels-last for coalesced gathers)
__global__ __launch_bounds__(256) void k_xT(const float* __restrict__ x,
                                            float* __restrict__ xT) {
  int i = blockIdx.x * 256 + threadIdx.x;   // B*SP*Cin = 2,359,296
  int c = i & 63;
  int rest = i >> 6;
  int p = rest % SP;
  int b = rest / SP;
  xT[i] = x[(b * Cin + c) * SP + p];
}

// weight [co][i][k] -> wT [k][i][co]
__global__ __launch_bounds__(256) void k_wT(const float* __restrict__ w,
                                            float* __restrict__ wT) {
  int idx = blockIdx.x * 256 + threadIdx.x; // k*4096 + i*64 + co ; 110592 total
  int co = idx & 63;
  int i = (idx >> 6) & 63;
  int k = idx >> 12;
  wT[idx] = w[(co * Cin + i) * K + k];
}

// offset conv: out channel = dim*27 + kpt. One thread computes all 3 dims for
// one (b, kpt, d, h, w) so the x neighborhood is read once for 3 outputs.
__global__ __launch_bounds__(256) void k_off(const float* __restrict__ x,
                                             const float* __restrict__ cw,
                                             const float* __restrict__ cb,
                                             float* __restrict__ off) {
  int bid = blockIdx.x;                 // 3888 = 2 * 27 * 8 * 9
  int chunk = bid % 9;
  int d = (bid / 9) & 7;
  int kpt = (bid / 72) % 27;
  int b = bid / 1944;
  int p = chunk * 256 + threadIdx.x;    // within-plane position
  int h = p / 48, w = p - (p / 48) * 48;

  float a0 = cb[kpt], a1 = cb[27 + kpt], a2 = cb[54 + kpt];
  const float* w0 = cw + kpt * 1728;
  const float* w1 = cw + (27 + kpt) * 1728;
  const float* w2 = cw + (54 + kpt) * 1728;
  const float* xb = x + b * Cin * SP;

  for (int i = 0; i < Cin; ++i) {
    const float* xc = xb + i * SP;
    const float* wi0 = w0 + i * 27;
    const float* wi1 = w1 + i * 27;
    const float* wi2 = w2 + i * 27;
#pragma unroll
    for (int kd = 0; kd < 3; ++kd) {
      int dd = d + kd - 1;
      bool vd = (unsigned)dd < (unsigned)Dd;
#pragma unroll
      for (int kh = 0; kh < 3; ++kh) {
        int hh = h + kh - 1;
        bool vh = vd && ((unsigned)hh < (unsigned)Hh);
        int rb = dd * PLANE + hh * 48;
#pragma unroll
        for (int kw = 0; kw < 3; ++kw) {
          int ww = w + kw - 1;
          bool v = vh && ((unsigned)ww < (unsigned)Wd);
          float xv = v ? xc[rb + ww] : 0.f;
          int t = kd * 9 + kh * 3 + kw;
          a0 = fmaf(xv, wi0[t], a0);
          a1 = fmaf(xv, wi1[t], a1);
          a2 = fmaf(xv, wi2[t], a2);
        }
      }
    }
  }
  int ob = b * 81 * SP + d * PLANE + p;
  off[ob + kpt * SP] = a0;
  off[ob + (27 + kpt) * SP] = a1;
  off[ob + (54 + kpt) * SP] = a2;
}

// fused trilinear gather + einsum. Block = 64 positions x 64 couts.
__global__ __launch_bounds__(256) void k_main(const float* __restrict__ xT,
                                              const float* __restrict__ off,
                                              const float* __restrict__ wT,
                                              const float* __restrict__ bias,
                                              float* __restrict__ out) {
  __shared__ __align__(16) float vals[64 * 68];  // [p][cin], stride 68 keeps f32x4 aligned
  __shared__ float wk[64 * 64];                  // [i][co]
  __shared__ int sidx[8 * 64];                   // [corner][p]
  __shared__ float swgt[8 * 64];

  const int t = threadIdx.x;
  const int bid = blockIdx.x;                    // 576 = 2 * 288
  const int b = bid / 288;
  const int p0 = (bid % 288) * 64;
  const int co = t & 63, pg = t >> 6;

  float acc[16];
#pragma unroll
  for (int j = 0; j < 16; ++j) acc[j] = 0.f;
  const float* xb = xT + b * SP * 64;
  const float* offb = off + b * 81 * SP;

  for (int k = 0; k < K; ++k) {
    __syncthreads();   // prev GEMM done reading vals/wk
#pragma unroll
    for (int r = 0; r < 16; ++r) wk[t + 256 * r] = wT[k * 4096 + t + 256 * r];
    if (t < 64) {
      int p = p0 + t;
      int d = p / PLANE;
      int rp = p - d * PLANE;
      int h = rp / 48;
      int w = rp - h * 48;
      int kd = k / 9, kh = (k % 9) / 3, kw2 = k % 3;
      float pd = (float)(d + kd - 1) + offb[k * SP + p];
      float ph = (float)(h + kh - 1) + offb[(27 + k) * SP + p];
      float pw = (float)(w + kw2 - 1) + offb[(54 + k) * SP + p];
      float df = floorf(pd), hf = floorf(ph), wf = floorf(pw);
      float fd = pd - df, fh = ph - hf, fw = pw - wf;
      int d0 = (int)df, h0 = (int)hf, w0i = (int)wf;
#pragma unroll
      for (int c = 0; c < 8; ++c) {
        int cd = c >> 2, ch = (c >> 1) & 1, cwb = c & 1;
        int di = d0 + cd, hi = h0 + ch, wi = w0i + cwb;
        bool v = ((unsigned)di < 8u) && ((unsigned)hi < 48u) && ((unsigned)wi < 48u);
        float wg = (cd ? fd : 1.f - fd) * (ch ? fh : 1.f - fh) * (cwb ? fw : 1.f - fw);
        sidx[c * 64 + t] = v ? ((di * 48 + hi) * 48 + wi) : -1;
        swgt[c * 64 + t] = wg;
      }
    }
    __syncthreads();
    // gather: lane = cin, wave-uniform position => broadcast idx/wgt, coalesced x reads
    for (int j = 0; j < 16; ++j) {
      int pl = pg * 16 + j;
      float v = 0.f;
#pragma unroll
      for (int c = 0; c < 8; ++c) {
        int ii = sidx[c * 64 + pl];
        if (ii >= 0) v = fmaf(swgt[c * 64 + pl], xb[ii * 64 + co], v);
      }
      vals[pl * 68 + co] = v;
    }
    __syncthreads();
    // GEMM: acc[p][co] += vals[p][i] * wk[i][co]
    for (int i = 0; i < 64; i += 4) {
      float4 wv;
      wv.x = wk[(i + 0) * 64 + co];
      wv.y = wk[(i + 1) * 64 + co];
      wv.z = wk[(i + 2) * 64 + co];
      wv.w = wk[(i + 3) * 64 + co];
#pragma unroll
      for (int j = 0; j < 16; ++j) {
        const float4 vv = *reinterpret_cast<const float4*>(&vals[(pg * 16 + j) * 68 + i]);
        acc[j] = fmaf(vv.x, wv.x, acc[j]);
        acc[j] = fmaf(vv.y, wv.y, acc[j]);
        acc[j] = fmaf(vv.z, wv.z, acc[j]);
        acc[j] = fmaf(vv.w, wv.w, acc[j]);
      }
    }
  }
  __syncthreads();
  // transpose through LDS for coalesced store
#pragma unroll
  for (int j = 0; j < 16; ++j) vals[co * 68 + pg * 16 + j] = acc[j];
  __syncthreads();
  {
    int p = t & 63;
    int cog = t >> 6;
#pragma unroll
    for (int r = 0; r < 16; ++r) {
      int c2 = cog * 16 + r;
      out[(b * Cout + c2) * SP + p0 + p] = vals[c2 * 68 + p] + bias[c2];
    }
  }
}

extern "C" void kernel_launch(void* const* d_in, const int* in_sizes, int n_in,
                              void* d_out, int out_size, void* d_ws, size_t ws_size,
                              hipStream_t stream) {
  const float* x = (const float*)d_in[0];
  const float* cw = (const float*)d_in[1];
  const float* cb = (const float*)d_in[2];
  const float* w = (const float*)d_in[3];
  const float* bias = (const float*)d_in[4];
  float* out = (float*)d_out;

  char* ws = (char*)d_ws;
  float* off = (float*)ws;                                   // 2*81*18432 f32 = 11,943,936 B
  float* xT = (float*)(ws + 11943936);                       // 2*18432*64 f32 = 9,437,184 B
  float* wT = (float*)(ws + 11943936 + 9437184);             // 27*64*64  f32 =   442,368 B

  hipLaunchKernelGGL(k_xT, dim3(9216), dim3(256), 0, stream, x, xT);
  hipLaunchKernelGGL(k_wT, dim3(432), dim3(256), 0, stream, w, wT);
  hipLaunchKernelGGL(k_off, dim3(3888), dim3(256), 0, stream, x, cw, cb, off);
  hipLaunchKernelGGL(k_main, dim3(576), dim3(256), 0, stream, xT, off, wT, bias, out);
}

// Round 2
// 827.910 us; speedup vs baseline: 1.8839x; 1.8839x over previous
//
#include <hip/hip_runtime.h>

namespace {
constexpr int Bn = 2, Cin = 64, Cout = 64;
constexpr int Dd = 8, Hh = 48, Wd = 48;
constexpr int K = 27;
constexpr int SP = Dd * Hh * Wd;   // 18432
constexpr int PLANE = Hh * Wd;     // 2304
constexpr int NTILE = SP / 64;     // 288 position tiles per batch
}

// x [B,C,D,H,W] -> xT [B, spatial, C]  (channels-last for coalesced gathers)
__global__ __launch_bounds__(256) void k_xT(const float* __restrict__ x,
                                            float* __restrict__ xT) {
  int i = blockIdx.x * 256 + threadIdx.x;   // B*SP*Cin = 2,359,296
  int c = i & 63;
  int rest = i >> 6;
  int p = rest % SP;
  int b = rest / SP;
  xT[i] = x[(b * Cin + c) * SP + p];
}

// weight [co][i][k] -> wT [k][i][co]
__global__ __launch_bounds__(256) void k_wT(const float* __restrict__ w,
                                            float* __restrict__ wT) {
  int idx = blockIdx.x * 256 + threadIdx.x; // k*4096 + i*64 + co ; 110592 total
  int co = idx & 63;
  int i = (idx >> 6) & 63;
  int k = idx >> 12;
  wT[idx] = w[(co * Cin + i) * K + k];
}

// offset conv: out channel = dim*27 + kpt. One thread computes all 3 dims for
// one (b, kpt, d, h, w) so the x neighborhood is read once for 3 outputs.
__global__ __launch_bounds__(256) void k_off(const float* __restrict__ x,
                                             const float* __restrict__ cw,
                                             const float* __restrict__ cb,
                                             float* __restrict__ off) {
  int bid = blockIdx.x;                 // 3888 = 2 * 27 * 8 * 9
  int chunk = bid % 9;
  int d = (bid / 9) & 7;
  int kpt = (bid / 72) % 27;
  int b = bid / 1944;
  int p = chunk * 256 + threadIdx.x;    // within-plane position
  int h = p / 48, w = p - (p / 48) * 48;

  float a0 = cb[kpt], a1 = cb[27 + kpt], a2 = cb[54 + kpt];
  const float* w0 = cw + kpt * 1728;
  const float* w1 = cw + (27 + kpt) * 1728;
  const float* w2 = cw + (54 + kpt) * 1728;
  const float* xb = x + b * Cin * SP;

  for (int i = 0; i < Cin; ++i) {
    const float* xc = xb + i * SP;
    const float* wi0 = w0 + i * 27;
    const float* wi1 = w1 + i * 27;
    const float* wi2 = w2 + i * 27;
#pragma unroll
    for (int kd = 0; kd < 3; ++kd) {
      int dd = d + kd - 1;
      bool vd = (unsigned)dd < (unsigned)Dd;
#pragma unroll
      for (int kh = 0; kh < 3; ++kh) {
        int hh = h + kh - 1;
        bool vh = vd && ((unsigned)hh < (unsigned)Hh);
        int rb = dd * PLANE + hh * 48;
#pragma unroll
        for (int kw = 0; kw < 3; ++kw) {
          int ww = w + kw - 1;
          bool v = vh && ((unsigned)ww < (unsigned)Wd);
          float xv = v ? xc[rb + ww] : 0.f;
          int t = kd * 9 + kh * 3 + kw;
          a0 = fmaf(xv, wi0[t], a0);
          a1 = fmaf(xv, wi1[t], a1);
          a2 = fmaf(xv, wi2[t], a2);
        }
      }
    }
  }
  int ob = b * 81 * SP + d * PLANE + p;
  off[ob + kpt * SP] = a0;
  off[ob + (27 + kpt) * SP] = a1;
  off[ob + (54 + kpt) * SP] = a2;
}

// Fused gather + GEMM, K-split across blocks. Block tile: 64 pos x 64 co,
// kper k-points; writes a partial [64co][64pos] tile to `part`.
// Thread GEMM tile: 4 co x 4 pos (register-blocked, b128 LDS reads only).
__global__ __launch_bounds__(256, 6) void k_mainp(const float* __restrict__ xT,
                                                  const float* __restrict__ off,
                                                  const float* __restrict__ wT,
                                                  float* __restrict__ part,
                                                  int kper) {
  __shared__ __align__(16) float vals[64 * 68];  // [cin][pos], row stride 68
  __shared__ __align__(16) unsigned scp[64 * 20]; // [pos][8 corners x (idx64,wgt)], row 20 words

  const int t = threadIdx.x;
  const int bid = blockIdx.x;                    // kc*576 + b*288 + tile
  const int kc = bid / 576;
  const int rem = bid - kc * 576;
  const int b = rem / NTILE;
  const int tile = rem - b * NTILE;
  const int p0 = tile * 64;

  const float* xb = xT + b * SP * 64;
  const float* offb = off + b * 81 * SP;

  const int cq = t & 15;   // co = 4*cq + r
  const int pq = t >> 4;   // pos = 4*pq + q
  float4 acc[4];
#pragma unroll
  for (int r = 0; r < 4; ++r) acc[r] = float4{0.f, 0.f, 0.f, 0.f};

  for (int kk = 0; kk < kper; ++kk) {
    const int k = kc * kper + kk;
    // ---- corner setup: pl = t&63, cg = t>>6 computes corners 2cg, 2cg+1
    {
      int pl = t & 63, cg = t >> 6;
      int p = p0 + pl;
      int d = p / PLANE;
      int rp = p - d * PLANE;
      int h = rp / 48;
      int w = rp - h * 48;
      int kd = k / 9, kh = (k % 9) / 3, kw2 = k % 3;
      float pd = (float)(d + kd - 1) + offb[k * SP + p];
      float ph = (float)(h + kh - 1) + offb[(27 + k) * SP + p];
      float pw = (float)(w + kw2 - 1) + offb[(54 + k) * SP + p];
      float df = floorf(pd), hf = floorf(ph), wf = floorf(pw);
      float fd = pd - df, fh = ph - hf, fw = pw - wf;
      int d0 = (int)df, h0 = (int)hf, w0i = (int)wf;
#pragma unroll
      for (int cc = 0; cc < 2; ++cc) {
        int c = cg * 2 + cc;
        int cd = c >> 2, ch = (c >> 1) & 1, cwb = c & 1;
        int di = d0 + cd, hi = h0 + ch, wi = w0i + cwb;
        bool v = ((unsigned)di < 8u) && ((unsigned)hi < 48u) && ((unsigned)wi < 48u);
        float wg = (cd ? fd : 1.f - fd) * (ch ? fh : 1.f - fh) * (cwb ? fw : 1.f - fw);
        int dic = min(max(di, 0), 7), hic = min(max(hi, 0), 47), wic = min(max(wi, 0), 47);
        int idx = (dic * 48 + hic) * 48 + wic;
        scp[pl * 20 + c * 2] = (unsigned)(idx * 64);
        scp[pl * 20 + c * 2 + 1] = __float_as_uint(v ? wg : 0.f);
      }
    }
    __syncthreads();
    // ---- gather: lane = cin, 16 positions per thread, branchless 8-corner blend
    {
      int co = t & 63, pg = t >> 6;
      for (int j = 0; j < 16; ++j) {
        int pl = pg * 16 + j;
        const uint4* sp4 = reinterpret_cast<const uint4*>(&scp[pl * 20]);
        uint4 q0 = sp4[0], q1 = sp4[1], q2 = sp4[2], q3 = sp4[3];
        float v = 0.f;
        v = fmaf(__uint_as_float(q0.y), xb[q0.x + co], v);
        v = fmaf(__uint_as_float(q0.w), xb[q0.z + co], v);
        v = fmaf(__uint_as_float(q1.y), xb[q1.x + co], v);
        v = fmaf(__uint_as_float(q1.w), xb[q1.z + co], v);
        v = fmaf(__uint_as_float(q2.y), xb[q2.x + co], v);
        v = fmaf(__uint_as_float(q2.w), xb[q2.z + co], v);
        v = fmaf(__uint_as_float(q3.y), xb[q3.x + co], v);
        v = fmaf(__uint_as_float(q3.w), xb[q3.z + co], v);
        vals[co * 68 + pl] = v;
      }
    }
    __syncthreads();
    // ---- GEMM: acc[r][q] += wT[k][i][4cq+r] * vals[i][4pq+q]
    {
      const float4* wk4 = reinterpret_cast<const float4*>(wT + k * 4096);
#pragma unroll 8
      for (int i = 0; i < 64; ++i) {
        float4 wv = wk4[i * 16 + cq];
        float4 vv = *reinterpret_cast<const float4*>(&vals[i * 68 + 4 * pq]);
        acc[0].x = fmaf(wv.x, vv.x, acc[0].x); acc[0].y = fmaf(wv.x, vv.y, acc[0].y);
        acc[0].z = fmaf(wv.x, vv.z, acc[0].z); acc[0].w = fmaf(wv.x, vv.w, acc[0].w);
        acc[1].x = fmaf(wv.y, vv.x, acc[1].x); acc[1].y = fmaf(wv.y, vv.y, acc[1].y);
        acc[1].z = fmaf(wv.y, vv.z, acc[1].z); acc[1].w = fmaf(wv.y, vv.w, acc[1].w);
        acc[2].x = fmaf(wv.z, vv.x, acc[2].x); acc[2].y = fmaf(wv.z, vv.y, acc[2].y);
        acc[2].z = fmaf(wv.z, vv.z, acc[2].z); acc[2].w = fmaf(wv.z, vv.w, acc[2].w);
        acc[3].x = fmaf(wv.w, vv.x, acc[3].x); acc[3].y = fmaf(wv.w, vv.y, acc[3].y);
        acc[3].z = fmaf(wv.w, vv.z, acc[3].z); acc[3].w = fmaf(wv.w, vv.w, acc[3].w);
      }
    }
    __syncthreads();  // protect scp/vals before next k iteration
  }

  // partial tile out: part[kc][b][tile][co][pos]
  float* pp = part + ((size_t)(kc * 2 + b) * NTILE + tile) * 4096;
#pragma unroll
  for (int r = 0; r < 4; ++r) {
    *reinterpret_cast<float4*>(pp + (4 * cq + r) * 64 + 4 * pq) = acc[r];
  }
}

// out[b][co][p] = bias[co] + sum_kc part[kc][b][tile][co][pos]
__global__ __launch_bounds__(256) void k_red(const float* __restrict__ part,
                                             const float* __restrict__ bias,
                                             float* __restrict__ out,
                                             int KC) {
  int i = blockIdx.x * 256 + threadIdx.x;  // 2,359,296
  int p = i % SP;
  int co = (i / SP) & 63;
  int b = i / (SP * 64);
  int tile = p >> 6, pos = p & 63;
  size_t base = ((size_t)b * NTILE + tile) * 4096 + co * 64 + pos;
  float s = bias[co];
  for (int kc = 0; kc < KC; ++kc) s += part[base + (size_t)kc * (2 * NTILE * 4096)];
  out[i] = s;
}

extern "C" void kernel_launch(void* const* d_in, const int* in_sizes, int n_in,
                              void* d_out, int out_size, void* d_ws, size_t ws_size,
                              hipStream_t stream) {
  const float* x = (const float*)d_in[0];
  const float* cw = (const float*)d_in[1];
  const float* cb = (const float*)d_in[2];
  const float* w = (const float*)d_in[3];
  const float* bias = (const float*)d_in[4];
  float* out = (float*)d_out;

  char* ws = (char*)d_ws;
  float* off = (float*)ws;                                   // 11,943,936 B
  float* xT = (float*)(ws + 11943936);                       //  9,437,184 B
  float* wT = (float*)(ws + 11943936 + 9437184);             //    442,368 B
  float* part = (float*)(ws + 21823488);                     // KC * 9,437,184 B

  // pick K-split factor by available workspace (deterministic: ws_size is fixed)
  int KC = (ws_size >= 21823488ULL + 9ULL * 9437184ULL) ? 9 : 3;
  int kper = 27 / KC;

  hipLaunchKernelGGL(k_xT, dim3(9216), dim3(256), 0, stream, x, xT);
  hipLaunchKernelGGL(k_wT, dim3(432), dim3(256), 0, stream, w, wT);
  hipLaunchKernelGGL(k_off, dim3(3888), dim3(256), 0, stream, x, cw, cb, off);
  hipLaunchKernelGGL(k_mainp, dim3(KC * 576), dim3(256), 0, stream, xT, off, wT, part, kper);
  hipLaunchKernelGGL(k_red, dim3(9216), dim3(256), 0, stream, part, bias, out, KC);
}